// Round 1
// baseline (1822.339 us; speedup 1.0000x reference)
//
#include <hip/hip_runtime.h>
#include <hip/hip_bf16.h>
#include <stdint.h>

// Problem constants
#define NIMG 96          // 32*3
#define N 512
#define IMG_ELEMS (N*N)                  // 262144
#define OUT_PLANE ((long long)NIMG * IMG_ELEMS)  // 25165824 elements per output

// ---------------------------------------------------------------------------
// Build orthonormal DCT-II matrix D[k][m] = s_k * cos(pi*(2m+1)*k/(2N))
// Exact integer angle reduction mod 2N*2=2048, then cospif for accuracy.
// ---------------------------------------------------------------------------
__global__ void build_D_kernel(float* __restrict__ D) {
    int idx = blockIdx.x * blockDim.x + threadIdx.x;
    if (idx >= IMG_ELEMS) return;
    int k = idx >> 9;          // row
    int m = idx & 511;         // col
    int r = ((2 * m + 1) * k) & 2047;     // (2m+1)k mod 4N, exact in int
    float c = cospif((float)r * (1.0f / 1024.0f));   // cos(pi * r / 1024)
    float s = (k == 0) ? 0.04419417382415922f /* sqrt(1/512) */
                       : 0.0625f              /* sqrt(2/512) = 1/16 */;
    D[idx] = c * s;
}

// ---------------------------------------------------------------------------
// Batched tiled SGEMM: C[b] = op(A[b]) * op(B[b])
//   TA=0: op(A)[i,k] = A[i*lda + k]      TA=1: op(A)[i,k] = A[k*lda + i]
//   TB=0: op(B)[k,j] = B[k*ldb + j]      TB=1: op(B)[k,j] = B[j*ldb + k]
// Batch strides sA/sB/sC (0 for shared constant operand).
// trilim >= 0: zero B elements whose (global row + global col) > trilim
//   (only meaningful for TB=0, where row=k, col=j in B's own coords).
// Requires M,N multiples of 64 and K multiple of 16.
// ---------------------------------------------------------------------------
#define BM 64
#define BN 64
#define BK 16

template<int TA, int TB>
__global__ __launch_bounds__(256) void sgemm_k(
    const float* __restrict__ A, long long sA, int lda,
    const float* __restrict__ B, long long sB, int ldb,
    float* __restrict__ C, long long sC, int ldc,
    int M, int Nn, int K, int trilim)
{
    __shared__ float As[BK][BM + 4];
    __shared__ float Bs[BK][BN + 4];

    const int bz = blockIdx.z;
    const float* Ab = A + (long long)bz * sA;
    const float* Bb = B + (long long)bz * sB;
    float* Cb = C + (long long)bz * sC;

    const int n0 = blockIdx.x * BN;
    const int m0 = blockIdx.y * BM;
    const int t  = threadIdx.x;
    const int tx = t & 15;
    const int ty = t >> 4;

    float acc[4][4] = {};

    for (int k0 = 0; k0 < K; k0 += BK) {
        // ---- load A tile into As[k][i] = op(A)[m0+i, k0+k] ----
        if (TA == 0) {
            int k = t & 15;
            int i = t >> 4;                 // 0..15
            #pragma unroll
            for (int r = 0; r < 4; ++r)
                As[k][i + 16 * r] = Ab[(long long)(m0 + i + 16 * r) * lda + k0 + k];
        } else {
            int i = t & 63;
            int k = t >> 6;                 // 0..3
            #pragma unroll
            for (int r = 0; r < 4; ++r)
                As[k + 4 * r][i] = Ab[(long long)(k0 + k + 4 * r) * lda + m0 + i];
        }
        // ---- load B tile into Bs[k][j] = op(B)[k0+k, n0+j] (with tri mask) ----
        if (TB == 0) {
            int j = t & 63;
            int k = t >> 6;                 // 0..3
            #pragma unroll
            for (int r = 0; r < 4; ++r) {
                int kk = k + 4 * r;
                float v = Bb[(long long)(k0 + kk) * ldb + n0 + j];
                if (trilim >= 0 && (k0 + kk + n0 + j) > trilim) v = 0.0f;
                Bs[kk][j] = v;
            }
        } else {
            int k = t & 15;
            int j = t >> 4;                 // 0..15
            #pragma unroll
            for (int r = 0; r < 4; ++r) {
                int jj = j + 16 * r;
                float v = Bb[(long long)(n0 + jj) * ldb + k0 + k];
                if (trilim >= 0 && (k0 + k + n0 + jj) > trilim) v = 0.0f;
                Bs[k][jj] = v;
            }
        }
        __syncthreads();

        #pragma unroll
        for (int kk = 0; kk < BK; ++kk) {
            float a[4], bv[4];
            #pragma unroll
            for (int r = 0; r < 4; ++r) a[r] = As[kk][ty * 4 + r];
            #pragma unroll
            for (int c = 0; c < 4; ++c) bv[c] = Bs[kk][tx * 4 + c];
            #pragma unroll
            for (int r = 0; r < 4; ++r)
                #pragma unroll
                for (int c = 0; c < 4; ++c)
                    acc[r][c] += a[r] * bv[c];
        }
        __syncthreads();
    }

    #pragma unroll
    for (int r = 0; r < 4; ++r) {
        float4 v = make_float4(acc[r][0], acc[r][1], acc[r][2], acc[r][3]);
        *reinterpret_cast<float4*>(&Cb[(long long)(m0 + ty * 4 + r) * ldc + n0 + tx * 4]) = v;
    }
}

// ---------------------------------------------------------------------------
// Launch
// d_in[0] = x [96, 512, 512] f32; d_in[1] = masks (unused, structure known)
// d_out = [LL, LH, HL, HH] each [96,512,512] f32
// d_ws: D (1MB) + dct2 (96*1MB)
// ---------------------------------------------------------------------------
extern "C" void kernel_launch(void* const* d_in, const int* in_sizes, int n_in,
                              void* d_out, int out_size, void* d_ws, size_t ws_size,
                              hipStream_t stream) {
    const float* x = (const float*)d_in[0];
    float* out = (float*)d_out;

    float* outLL = out + 0 * OUT_PLANE;
    float* outLH = out + 1 * OUT_PLANE;
    float* outHL = out + 2 * OUT_PLANE;
    float* outHH = out + 3 * OUT_PLANE;

    float* Dm   = (float*)d_ws;                       // 512*512 f32
    float* dct2 = Dm + IMG_ELEMS;                     // 96 * 512*512 f32

    const long long S = IMG_ELEMS;  // per-image stride

    // 0. build DCT matrix
    build_D_kernel<<<dim3(IMG_ELEMS / 256), dim3(256), 0, stream>>>(Dm);

    // 1. T1 = D @ x  -> outLH (scratch)
    sgemm_k<0, 0><<<dim3(N / BN, N / BM, NIMG), 256, 0, stream>>>(
        Dm, 0, N, x, S, N, outLH, S, N, N, N, N, -1);

    // 2. dct2 = T1 @ D^T -> ws
    sgemm_k<0, 1><<<dim3(N / BN, N / BM, NIMG), 256, 0, stream>>>(
        outLH, S, N, Dm, 0, N, dct2, S, N, N, N, N, -1);

    // 3. LL = x (identity: IDCT(DCT(x)) with all-ones mask)
    hipMemcpyAsync(outLL, x, (size_t)OUT_PLANE * sizeof(float),
                   hipMemcpyDeviceToDevice, stream);

    // 4. HH: U = D^T @ (dct2 . tri511) -> outLH (scratch, overwrites T1)
    sgemm_k<1, 0><<<dim3(N / BN, N / BM, NIMG), 256, 0, stream>>>(
        Dm, 0, N, dct2, S, N, outLH, S, N, N, N, N, 511);
    //    outHH = U @ D
    sgemm_k<0, 0><<<dim3(N / BN, N / BM, NIMG), 256, 0, stream>>>(
        outLH, S, N, Dm, 0, N, outHH, S, N, N, N, N, -1);

    // 5. HL: U2 = D^T[:, :256] @ (dct2[:256,:256] . tri255)
    //    U2 (512x256) colocated in dead rows 256..511 of each dct2 image block
    float* U2 = dct2 + 256 * N;
    sgemm_k<1, 0><<<dim3(256 / BN, N / BM, NIMG), 256, 0, stream>>>(
        Dm, 0, N, dct2, S, N, U2, S, 256, N, 256, 256, 255);
    //    outHL = U2 @ D[:256, :]
    sgemm_k<0, 0><<<dim3(N / BN, N / BM, NIMG), 256, 0, stream>>>(
        U2, S, 256, Dm, 0, N, outHL, S, N, N, N, 256, -1);

    // 6. LH: U3 = D^T[:, :128] @ (dct2[:128,:128] . tri127)
    //    U3 (512x128) colocated in dead rows 128..255 of each dct2 image block
    float* U3 = dct2 + 128 * N;
    sgemm_k<1, 0><<<dim3(128 / BN, N / BM, NIMG), 256, 0, stream>>>(
        Dm, 0, N, dct2, S, N, U3, S, 128, N, 128, 128, 127);
    //    outLH = U3 @ D[:128, :]  (reads U3 from ws, writes final LH)
    sgemm_k<0, 0><<<dim3(N / BN, N / BM, NIMG), 256, 0, stream>>>(
        U3, S, 128, Dm, 0, N, outLH, S, N, N, N, 128, -1);
}

// Round 2
// 363.952 us; speedup vs baseline: 5.0071x; 5.0071x over previous
//
#include <hip/hip_runtime.h>
#include <hip/hip_bf16.h>
#include <stdint.h>

#define NIMG 96
#define N 512
#define IMG (N*N)
#define OUT_PLANE ((long long)NIMG * IMG)

typedef __attribute__((ext_vector_type(8))) _Float16 f16x8;
typedef __attribute__((ext_vector_type(4))) float f32x4;
typedef unsigned short u16;

__device__ inline u16 f2h(float v) {
    _Float16 h = (_Float16)v;
    return __builtin_bit_cast(u16, h);
}

__device__ inline void gload16(const void* g, void* l) {
    __builtin_amdgcn_global_load_lds(
        (const __attribute__((address_space(1))) void*)g,
        (__attribute__((address_space(3))) void*)l, 16, 0, 0);
}

// ---------------------------------------------------------------------------
// Build D (orthonormal DCT-II) in f16, both row-major and col-major layouts.
// Exact integer angle reduction mod 2048, cospif for accuracy.
// ---------------------------------------------------------------------------
__global__ void build_D(u16* __restrict__ Drm, u16* __restrict__ Dcm) {
    int idx = blockIdx.x * 256 + threadIdx.x;
    int k = idx >> 9, m = idx & 511;
    int r = ((2 * m + 1) * k) & 2047;
    float c = cospif((float)r * (1.0f / 1024.0f));
    float s = (k == 0) ? 0.04419417382415922f : 0.0625f;
    u16 h = f2h(c * s);
    Drm[k * 512 + m] = h;
    Dcm[m * 512 + k] = h;
}

// ---------------------------------------------------------------------------
// x fp32 row-major -> Xcm f16 col-major (per image), LDS-tiled transpose.
// ---------------------------------------------------------------------------
__global__ __launch_bounds__(256) void conv_x(const float* __restrict__ x,
                                              u16* __restrict__ Xcm) {
    __shared__ float t[32][33];
    const long long base = (long long)blockIdx.z * IMG;
    const int r0 = blockIdx.y * 32, c0 = blockIdx.x * 32;
    const int tr = threadIdx.x >> 3;
    const int tc = (threadIdx.x & 7) * 4;
    float4 v = *(const float4*)&x[base + (long long)(r0 + tr) * N + c0 + tc];
    t[tr][tc + 0] = v.x; t[tr][tc + 1] = v.y;
    t[tr][tc + 2] = v.z; t[tr][tc + 3] = v.w;
    __syncthreads();
    ushort4 h;
    h.x = f2h(t[tc + 0][tr]); h.y = f2h(t[tc + 1][tr]);
    h.z = f2h(t[tc + 2][tr]); h.w = f2h(t[tc + 3][tr]);
    *(ushort4*)&Xcm[base + (long long)(c0 + tr) * N + r0 + tc] = h;
}

// ---------------------------------------------------------------------------
// Masked sub-block copy: Z[j*W+i] = (i+j<=lim) ? Ycm[j*512+i] : 0  (per image)
// ---------------------------------------------------------------------------
__global__ __launch_bounds__(256) void maskcopy(const u16* __restrict__ Y,
                                                u16* __restrict__ Z,
                                                int W, int lim) {
    long long idx = (long long)blockIdx.x * 256 + threadIdx.x; // 1 thread = 4 elems
    int wq = W >> 2;
    long long perimg = (long long)W * wq;
    int img = (int)(idx / perimg);
    long long rem = idx % perimg;
    int j = (int)(rem / wq);
    int i = (int)(rem % wq) * 4;
    ushort4 v = *(const ushort4*)&Y[(long long)img * IMG + (long long)j * N + i];
    if (i + 0 + j > lim) v.x = 0;
    if (i + 1 + j > lim) v.y = 0;
    if (i + 2 + j > lim) v.z = 0;
    if (i + 3 + j > lim) v.w = 0;
    *(ushort4*)&Z[(long long)img * W * W + (long long)j * W + i] = v;
}

// ---------------------------------------------------------------------------
// f16 MFMA GEMM: C = A(row-major) * B(stored col-major: Bcm[n][k]=B[k][n]).
// 128x128 tile, BK=32, 4 waves (64x64 each), mfma_f32_16x16x32_f16.
// EPI: 0 = fp32 row-major, 1 = f16 row-major, 2 = f16 col-major with
//      anti-triangular mask (r+c<=trilim kept; use huge trilim for none).
// M,N must be multiples of 128 (from grid), K multiple of 32.
// ---------------------------------------------------------------------------
template<int EPI>
__global__ __launch_bounds__(256) void gemm16(
    const u16* __restrict__ A, long long sA, int lda,
    const u16* __restrict__ B, long long sB, int ldb,
    void* __restrict__ Cv, long long sC, int ldc,
    int K, int trilim)
{
    __shared__ u16 As[2][128 * 32];
    __shared__ u16 Bs[2][128 * 32];

    const int bz = blockIdx.z;
    const int m0 = blockIdx.y * 128;
    const int n0 = blockIdx.x * 128;
    const int tid = threadIdx.x;
    const int wave = tid >> 6;
    const int lane = tid & 63;

    const u16* __restrict__ Ab = A + (long long)bz * sA;
    const u16* __restrict__ Bb = B + (long long)bz * sB;

    // staging: per wave 2 issues per operand; lane covers (row = lane>>2, 8 k's)
    const int srow = lane >> 2;
    const int sc8  = (lane & 3) * 8;
    const int war  = wave * 32;

    // fragments
    const int fr  = lane & 15;
    const int kg8 = (lane >> 4) * 8;
    const int wr  = (wave >> 1) * 64;
    const int wc  = (wave & 1) * 64;

    int aoff[4], boff[4];
    #pragma unroll
    for (int i = 0; i < 4; ++i) {
        aoff[i] = (wr + i * 16 + fr) * 32 + kg8;
        boff[i] = (wc + i * 16 + fr) * 32 + kg8;
    }

    f32x4 acc[4][4];
    #pragma unroll
    for (int i = 0; i < 4; ++i)
        #pragma unroll
        for (int j = 0; j < 4; ++j)
            acc[i][j] = (f32x4){0.0f, 0.0f, 0.0f, 0.0f};

    auto stage = [&](int buf, int k0) {
        #pragma unroll
        for (int i = 0; i < 2; ++i) {
            int r = war + i * 16;
            gload16(Ab + (long long)(m0 + r + srow) * lda + k0 + sc8, &As[buf][r * 32]);
            gload16(Bb + (long long)(n0 + r + srow) * ldb + k0 + sc8, &Bs[buf][r * 32]);
        }
    };
    auto compute = [&](int buf) {
        f16x8 af[4], bf[4];
        #pragma unroll
        for (int i = 0; i < 4; ++i) af[i] = *(const f16x8*)&As[buf][aoff[i]];
        #pragma unroll
        for (int j = 0; j < 4; ++j) bf[j] = *(const f16x8*)&Bs[buf][boff[j]];
        #pragma unroll
        for (int i = 0; i < 4; ++i)
            #pragma unroll
            for (int j = 0; j < 4; ++j)
                acc[i][j] = __builtin_amdgcn_mfma_f32_16x16x32_f16(af[i], bf[j], acc[i][j], 0, 0, 0);
    };

    const int nb = K >> 5;
    stage(0, 0);
    __syncthreads();
    int cur = 0;
    for (int t = 0; t < nb - 1; ++t) {
        stage(cur ^ 1, (t + 1) * 32);
        compute(cur);
        __syncthreads();
        cur ^= 1;
    }
    compute(cur);

    // ---- epilogue ----
    const int rb = (lane >> 4) * 4;
    if (EPI == 0) {
        float* Cb = (float*)Cv + (long long)bz * sC;
        #pragma unroll
        for (int i = 0; i < 4; ++i)
            #pragma unroll
            for (int j = 0; j < 4; ++j) {
                int r = m0 + wr + i * 16 + rb;
                int c = n0 + wc + j * 16 + fr;
                #pragma unroll
                for (int g = 0; g < 4; ++g)
                    Cb[(long long)(r + g) * ldc + c] = acc[i][j][g];
            }
    } else if (EPI == 1) {
        u16* Cb = (u16*)Cv + (long long)bz * sC;
        #pragma unroll
        for (int i = 0; i < 4; ++i)
            #pragma unroll
            for (int j = 0; j < 4; ++j) {
                int r = m0 + wr + i * 16 + rb;
                int c = n0 + wc + j * 16 + fr;
                #pragma unroll
                for (int g = 0; g < 4; ++g)
                    Cb[(long long)(r + g) * ldc + c] = f2h(acc[i][j][g]);
            }
    } else {
        u16* Cb = (u16*)Cv + (long long)bz * sC;
        #pragma unroll
        for (int i = 0; i < 4; ++i)
            #pragma unroll
            for (int j = 0; j < 4; ++j) {
                int r = m0 + wr + i * 16 + rb;     // 4 consecutive rows
                int c = n0 + wc + j * 16 + fr;     // fixed col
                ushort4 h;
                float v0 = ((r + 0) + c <= trilim) ? acc[i][j][0] : 0.0f;
                float v1 = ((r + 1) + c <= trilim) ? acc[i][j][1] : 0.0f;
                float v2 = ((r + 2) + c <= trilim) ? acc[i][j][2] : 0.0f;
                float v3 = ((r + 3) + c <= trilim) ? acc[i][j][3] : 0.0f;
                h.x = f2h(v0); h.y = f2h(v1); h.z = f2h(v2); h.w = f2h(v3);
                *(ushort4*)&Cb[(long long)c * ldc + r] = h;   // col-major 8B store
            }
    }
}

// ---------------------------------------------------------------------------
// Orchestration. All intermediates f16. ws layout (bytes), 97 MB total:
//   Drm @0 (512K) | Dcm @512K (512K) | Xcm/Ycm @1M (48M) | region @49M (48M)
//   region: T1 / U / U2 / U3 @ +0 ; Y2 @ +24M ; Y3 @ +36M   (lifetimes disjoint)
// ---------------------------------------------------------------------------
extern "C" void kernel_launch(void* const* d_in, const int* in_sizes, int n_in,
                              void* d_out, int out_size, void* d_ws, size_t ws_size,
                              hipStream_t stream) {
    const float* x = (const float*)d_in[0];
    float* out = (float*)d_out;
    float* outLL = out + 0 * OUT_PLANE;
    float* outLH = out + 1 * OUT_PLANE;
    float* outHL = out + 2 * OUT_PLANE;
    float* outHH = out + 3 * OUT_PLANE;

    char* ws = (char*)d_ws;
    u16* Drm = (u16*)(ws);                                  // D row-major  (= Dt col-major)
    u16* Dcm = (u16*)(ws + 524288);                         // D col-major  (= Dt row-major)
    u16* Xcm = (u16*)(ws + 1048576);                        // 48 MB
    u16* Ycm = Xcm;                                         // overwrites Xcm after S1
    char* reg = ws + 51380224;                              // 48 MB region
    u16* T1 = (u16*)reg;
    u16* U  = (u16*)reg;
    u16* U2 = (u16*)reg;
    u16* U3 = (u16*)reg;
    u16* Y2 = (u16*)(reg + 25165824);
    u16* Y3 = (u16*)(reg + 37748736);

    const long long S = IMG;
    const int BIG = 1 << 30;

    build_D<<<dim3(IMG / 256), 256, 0, stream>>>(Drm, Dcm);
    conv_x<<<dim3(16, 16, NIMG), 256, 0, stream>>>(x, Xcm);

    // S1: T1 = D @ X          (A=Drm shared, B=Xcm) -> f16 row-major
    gemm16<1><<<dim3(4, 4, NIMG), 256, 0, stream>>>(
        Drm, 0, 512, Xcm, S, 512, T1, S, 512, 512, 0);
    // S2: Y = T1 @ Dt         (B col-major of Dt = Drm) -> Ycm masked tri511
    gemm16<2><<<dim3(4, 4, NIMG), 256, 0, stream>>>(
        T1, S, 512, Drm, 0, 512, Ycm, S, 512, 512, 511);
    // S3: U^T = Ym^T @ D      (A=Ycm, B=Dcm) -> col-major write = U row-major
    gemm16<2><<<dim3(4, 4, NIMG), 256, 0, stream>>>(
        Ycm, S, 512, Dcm, 0, 512, U, S, 512, 512, BIG);
    // S4: HH = U @ D          -> fp32 row-major
    gemm16<0><<<dim3(4, 4, NIMG), 256, 0, stream>>>(
        U, S, 512, Dcm, 0, 512, outHH, S, 512, 512, 0);

    // masked sub-blocks of Y for HL / LH
    maskcopy<<<dim3(NIMG * 256 * 256 / 4 / 256), 256, 0, stream>>>(Ycm, Y2, 256, 255);
    maskcopy<<<dim3(NIMG * 128 * 128 / 4 / 256), 256, 0, stream>>>(Ycm, Y3, 128, 127);

    // S5: U2^T = Y2^T @ D[0:256,:]  (M=256,K=256) -> col-major = U2 row-major
    gemm16<2><<<dim3(4, 2, NIMG), 256, 0, stream>>>(
        Y2, 256 * 256, 256, Dcm, 0, 512, U2, 512 * 256, 256, 256, BIG);
    // S6: HL = U2 @ D[0:256,:]      (K=256) -> fp32
    gemm16<0><<<dim3(4, 4, NIMG), 256, 0, stream>>>(
        U2, 512 * 256, 256, Dcm, 0, 512, outHL, S, 512, 256, 0);

    // S7: U3^T = Y3^T @ D[0:128,:]  (M=128,K=128) -> col-major = U3 row-major
    gemm16<2><<<dim3(4, 1, NIMG), 256, 0, stream>>>(
        Y3, 128 * 128, 128, Dcm, 0, 512, U3, 512 * 128, 128, 128, BIG);
    // S8: LH = U3 @ D[0:128,:]      (K=128) -> fp32
    gemm16<0><<<dim3(4, 4, NIMG), 256, 0, stream>>>(
        U3, 512 * 128, 128, Dcm, 0, 512, outLH, S, 512, 128, 0);

    // LL = x (all-ones mask: IDCT(DCT(x)) = x)
    hipMemcpyAsync(outLL, x, (size_t)OUT_PLANE * sizeof(float),
                   hipMemcpyDeviceToDevice, stream);
}